// Round 14
// baseline (156.400 us; speedup 1.0000x reference)
//
#include <hip/hip_runtime.h>
#include <hip/hip_bf16.h>

// B=2, T=2048, C=1024, H=16, D=64. bf16 in/out (runtime dtype detect, inline per block).
// k_prep (768 blocks) -> k_gemm_qkv v4: 256x256 tile, BK=64, 8 waves/512thr,
// 4-PHASE K-tile schedule (m201-style): each phase = {ds_read subtile, stage-issue,
// raw s_barrier, setprio+16 MFMA, s_barrier}; all 4 stage units of K-tile kt+1
// issue in phases 0-1 -> the per-K-tile vmcnt(0) gate has 3-4 phases (~600cy) of
// compute cover (sources L2-warm). LDS 128KB 2-buf; XOR-8 both-sides swizzle
// (slot s of row r holds chunk s^(r&7); linear gl_lds dest, pre-swizzled source).
// 192 blocks (16m x 12n), XCD-bijective. R11 lesson: monolithic 2-barrier K-step
// at 1 block/CU stalls (occ 14%); m201 proves the phase-interleave fixes it at the
// SAME 1-block/CU. 256^2 halves LDS-traffic-per-FLOP vs 128^2 (the binding pipe).
// -> k_attn v11 (unchanged): fragment-order K2/V2, zero staging/barriers,
// cross-trip QK/softmax pipeline. R5 lesson: no VGPR squeeze.
// K2 idx = (bh*32+t)*4096 + p*2048 + nt*1024 + kh*512 + lane*8 + j
// V2 idx = (bh*32+t)*4096 + p*2048 + dt*512 + lane*8 + j
// ws: xb@0(8MB); wt@8MB(6MB); qk@16MB(16MB); K2@32MB(8MB); V2@40MB(8MB)

#define CDIM  1024
#define C3    3072
#define HS    64
#define TLEN  2048
#define KVT   64
#define SCL   0.1803368801111204f   // (1/8) * log2(e)

typedef __attribute__((ext_vector_type(8))) short bf16x8;
typedef __attribute__((ext_vector_type(4))) float f32x4;
typedef __attribute__((ext_vector_type(4))) unsigned short u16x4;

__device__ __forceinline__ unsigned short f2b(float f) {
    unsigned u = __float_as_uint(f);
    unsigned r = (u + 0x7FFFu + ((u >> 16) & 1u)) >> 16;
    return (unsigned short)r;
}
__device__ __forceinline__ float b2f(unsigned short u) {
    return __uint_as_float(((unsigned)u) << 16);
}
__device__ __forceinline__ float fexp2(float x) {
    return __builtin_amdgcn_exp2f(x);
}
__device__ __forceinline__ unsigned pkbf(float a, float b) {
    float2 f; f.x = a; f.y = b;
    __hip_bfloat162 h = __float22bfloat162_rn(f);
    union { __hip_bfloat162 h2; unsigned u; } c;
    c.h2 = h;
    return c.u;
}
__device__ __forceinline__ void gl_lds16(const unsigned short* g, unsigned short* l) {
    __builtin_amdgcn_global_load_lds((const __attribute__((address_space(1))) void*)g,
                                     (__attribute__((address_space(3))) void*)l, 16, 0, 0);
}
// bf16 iff "exponent" bits of low halfword concentrate in the normal range.
__device__ __forceinline__ int detect_bf(const void* bias, int lane) {
    unsigned w = ((const unsigned*)bias)[lane];
    unsigned e = (w >> 7) & 0xFF;
    unsigned long long m = __ballot(e >= 100 && e <= 135);
    return __popcll(m) >= 48;
}

// In-register S^T -> PV-B-fragment exchange.
__device__ __forceinline__ void plswap(unsigned x, unsigned& y0, unsigned& y1) {
    unsigned aa = x, bb = x;
    asm("v_permlane32_swap_b32 %0, %1" : "+v"(aa), "+v"(bb));
    asm("v_permlane16_swap_b32 %0, %1" : "+v"(aa), "+v"(bb));
    y0 = aa; y1 = bb;
}
__device__ __forceinline__ bf16x8 xfrag(unsigned x00, unsigned x01,
                                        unsigned x10, unsigned x11, int qsel) {
    unsigned y000, y100, y001, y101, y010, y110, y011, y111;
    plswap(x00, y000, y100);
    plswap(x01, y001, y101);
    plswap(x10, y010, y110);
    plswap(x11, y011, y111);
    union { unsigned u[4]; bf16x8 v; } r;
    r.u[0] = qsel ? y010 : y000;
    r.u[1] = qsel ? y011 : y001;
    r.u[2] = qsel ? y110 : y100;
    r.u[3] = qsel ? y111 : y101;
    return r.v;
}

// prep: 768 blocks. Each transposes one w tile; fp32 path converts x stripes
// bid, bid+768, bid+1536 with float4 loads.
__global__ __launch_bounds__(256) void k_prep(const void* __restrict__ w,
                                              const void* __restrict__ x,
                                              const void* __restrict__ bias,
                                              unsigned short* __restrict__ wt,
                                              unsigned short* __restrict__ xb) {
    __shared__ unsigned short tile[64 * 66];
    int t = threadIdx.x;
    int isbf = detect_bf(bias, t & 63);
    int bid = blockIdx.x;

    {
        int n0 = (bid % 48) * 64;
        int k0 = (bid / 48) * 64;
        for (int i = 0; i < 16; ++i) {
            int idx = t + i * 256;
            int r = idx >> 6, c = idx & 63;
            unsigned short v;
            if (isbf) v = ((const unsigned short*)w)[(k0 + r) * C3 + n0 + c];
            else      v = f2b(((const float*)w)[(k0 + r) * C3 + n0 + c]);
            tile[r * 66 + c] = v;
        }
        __syncthreads();
        for (int i = 0; i < 16; ++i) {
            int idx = t + i * 256;
            int r = idx >> 6, c = idx & 63;
            wt[(n0 + r) * CDIM + k0 + c] = tile[c * 66 + r];
        }
    }
    if (!isbf) {
        const float4* s = (const float4*)x;
        uint2* d = (uint2*)xb;
        for (int sb = bid; sb < 2048; sb += 768) {
            int base = sb * 512;
            for (int j = t; j < 512; j += 256) {
                float4 v = s[base + j];
                uint2 o_;
                o_.x = (unsigned)f2b(v.x) | ((unsigned)f2b(v.y) << 16);
                o_.y = (unsigned)f2b(v.z) | ((unsigned)f2b(v.w) << 16);
                d[base + j] = o_;
            }
        }
    }
}

// GEMM v4: 256x256, BK=64, 8 waves (2Mx4N), 512 thr, 4-phase K-tile schedule.
// LDS: As[2][256][64] + Bs[2][256][64] shorts = 128KB. Phase(mh,ks):
// ds_read A-frags mh*4..mh*4+3 (+B frags at mh==0) -> stage (ph0: A of kt+1,
// ph1: B of kt+1) -> barrier -> 16 MFMA -> barrier. vmcnt(0) gate once per K-tile
// with 3-4 phases of cover. Grid 192 (16m x 12n), XCD-bijective (192%8==0).
__global__ __launch_bounds__(512, 2) void k_gemm_qkv(const void* __restrict__ xraw,
                                                     const unsigned short* __restrict__ xb,
                                                     const void* __restrict__ biasraw,
                                                     const unsigned short* __restrict__ Bt,
                                                     unsigned short* __restrict__ qk,
                                                     unsigned short* __restrict__ k2,
                                                     unsigned short* __restrict__ v2) {
    __shared__ __align__(16) unsigned short As[2 * 16384];   // 64KB
    __shared__ __align__(16) unsigned short Bs[2 * 16384];   // 64KB
    int tid  = threadIdx.x;
    int lane = tid & 63, wv = tid >> 6;            // wv 0..7
    int quad = lane >> 4, l16 = lane & 15;
    int isbf = detect_bf(biasraw, lane);
    const unsigned short* A = isbf ? (const unsigned short*)xraw : xb;

    // XCD-aware bijective swizzle: 192 blocks, 8 XCDs, 24 per XCD chunk.
    int lin = blockIdx.x;
    int swz = (lin & 7) * 24 + (lin >> 3);
    int m0 = (swz / 12) * 256, n0 = (swz % 12) * 256;
    int wr = wv >> 2, wc = wv & 3;                 // wave 2x4 grid

    f32x4 acc[8][4] = {};

    // staging: per matrix per half: rows r0 and r0+64 (r0 = tid>>3), chunk-slot
    // tid&7 holds source chunk (tid&7)^(r0&7).  Dest linear: half*8192 + tid*8
    // (+4096 for the r0+64 chunk). Source ptrs at k=0:
    int r0 = tid >> 3;                              // 0..63
    int c0 = (((tid & 7) ^ (r0 & 7)) * 8);
    const unsigned short* aS0 = A  + (m0 + r0) * CDIM + c0;         // A half0
    const unsigned short* aS1 = aS0 + 128 * CDIM;                   // A half1
    const unsigned short* bS0 = Bt + (n0 + r0) * CDIM + c0;
    const unsigned short* bS1 = bS0 + 128 * CDIM;

    // trip-invariant ds_read offsets (shorts): row part + k-chunk slot
    int sw8 = l16 & 7;
    int arow = (wr * 128 + l16) * 64;
    int brow = (wc * 64  + l16) * 64;
    int kc0 = ((quad)     ^ sw8) * 8;              // ks=0 chunks 0..3
    int kc1 = ((4 + quad) ^ sw8) * 8;              // ks=1 chunks 4..7

    // prologue: stage K-tile 0 into buf0 (8 gl_lds), drain, barrier
    gl_lds16(aS0,             As + tid * 8);
    gl_lds16(aS0 + 64 * CDIM, As + tid * 8 + 4096);
    gl_lds16(aS1,             As + 8192 + tid * 8);
    gl_lds16(aS1 + 64 * CDIM, As + 8192 + tid * 8 + 4096);
    gl_lds16(bS0,             Bs + tid * 8);
    gl_lds16(bS0 + 64 * CDIM, Bs + tid * 8 + 4096);
    gl_lds16(bS1,             Bs + 8192 + tid * 8);
    gl_lds16(bS1 + 64 * CDIM, Bs + 8192 + tid * 8 + 4096);
    asm volatile("s_waitcnt vmcnt(0)" ::: "memory");
    __builtin_amdgcn_s_barrier();

    for (int kt = 0; kt < 16; ++kt) {
        int cur = kt & 1;
        const unsigned short* Ac = As + cur * 16384;
        const unsigned short* Bc = Bs + cur * 16384;
        unsigned short* Anx = As + (cur ^ 1) * 16384;
        unsigned short* Bnx = Bs + (cur ^ 1) * 16384;
        bool st = (kt < 15);
        int kof = (kt + 1) * 64;

        // ---- phase 0: mh=0, ks=0 ----
        bf16x8 afr[4], bfv0[4];
        #pragma unroll
        for (int mt = 0; mt < 4; ++mt)
            afr[mt] = *(const bf16x8*)&Ac[arow + mt * 1024 + kc0];
        #pragma unroll
        for (int nt = 0; nt < 4; ++nt)
            bfv0[nt] = *(const bf16x8*)&Bc[brow + nt * 1024 + kc0];
        if (st) {   // stage A of kt+1 (both halves)
            gl_lds16(aS0 + kof,             Anx + tid * 8);
            gl_lds16(aS0 + 64 * CDIM + kof, Anx + tid * 8 + 4096);
            gl_lds16(aS1 + kof,             Anx + 8192 + tid * 8);
            gl_lds16(aS1 + 64 * CDIM + kof, Anx + 8192 + tid * 8 + 4096);
        }
        __builtin_amdgcn_s_barrier();
        __builtin_amdgcn_s_setprio(1);
        #pragma unroll
        for (int mt = 0; mt < 4; ++mt)
            #pragma unroll
            for (int nt = 0; nt < 4; ++nt)
                acc[mt][nt] = __builtin_amdgcn_mfma_f32_16x16x32_bf16(afr[mt], bfv0[nt], acc[mt][nt], 0, 0, 0);
        __builtin_amdgcn_s_setprio(0);
        __builtin_amdgcn_s_barrier();

        // ---- phase 1: mh=1, ks=0 ----
        #pragma unroll
        for (int mt = 0; mt < 4; ++mt)
            afr[mt] = *(const bf16x8*)&Ac[arow + (4 + mt) * 1024 + kc0];
        if (st) {   // stage B of kt+1 (both halves)
            gl_lds16(bS0 + kof,             Bnx + tid * 8);
            gl_lds16(bS0 + 64 * CDIM + kof, Bnx + tid * 8 + 4096);
            gl_lds16(bS1 + kof,             Bnx + 8192 + tid * 8);
            gl_lds16(bS1 + 64 * CDIM + kof, Bnx + 8192 + tid * 8 + 4096);
        }
        __builtin_amdgcn_s_barrier();
        __builtin_amdgcn_s_setprio(1);
        #pragma unroll
        for (int mt = 0; mt < 4; ++mt)
            #pragma unroll
            for (int nt = 0; nt < 4; ++nt)
                acc[4 + mt][nt] = __builtin_amdgcn_mfma_f32_16x16x32_bf16(afr[mt], bfv0[nt], acc[4 + mt][nt], 0, 0, 0);
        __builtin_amdgcn_s_setprio(0);
        __builtin_amdgcn_s_barrier();

        // ---- phase 2: mh=0, ks=1 ----
        bf16x8 bfv1[4];
        #pragma unroll
        for (int mt = 0; mt < 4; ++mt)
            afr[mt] = *(const bf16x8*)&Ac[arow + mt * 1024 + kc1];
        #pragma unroll
        for (int nt = 0; nt < 4; ++nt)
            bfv1[nt] = *(const bf16x8*)&Bc[brow + nt * 1024 + kc1];
        __builtin_amdgcn_s_barrier();
        __builtin_amdgcn_s_setprio(1);
        #pragma unroll
        for (int mt = 0; mt < 4; ++mt)
            #pragma unroll
            for (int nt = 0; nt < 4; ++nt)
                acc[mt][nt] = __builtin_amdgcn_mfma_f32_16x16x32_bf16(afr[mt], bfv1[nt], acc[mt][nt], 0, 0, 0);
        __builtin_amdgcn_s_setprio(0);
        __builtin_amdgcn_s_barrier();

        // ---- phase 3: mh=1, ks=1 ----
        #pragma unroll
        for (int mt = 0; mt < 4; ++mt)
            afr[mt] = *(const bf16x8*)&Ac[arow + (4 + mt) * 1024 + kc1];
        __builtin_amdgcn_s_barrier();
        __builtin_amdgcn_s_setprio(1);
        #pragma unroll
        for (int mt = 0; mt < 4; ++mt)
            #pragma unroll
            for (int nt = 0; nt < 4; ++nt)
                acc[4 + mt][nt] = __builtin_amdgcn_mfma_f32_16x16x32_bf16(afr[mt], bfv1[nt], acc[4 + mt][nt], 0, 0, 0);
        __builtin_amdgcn_s_setprio(0);
        // K-tile gate: kt+1's 16 loads were issued 2-4 phases ago (covered);
        // wait them all, then barrier so every wave sees the staged tile.
        asm volatile("s_waitcnt vmcnt(0)" ::: "memory");
        __builtin_amdgcn_s_barrier();
    }

    // epilogue: three output regions (256-wide block lies entirely in one)
    if (n0 < 1024) {
        for (int mt = 0; mt < 8; ++mt) {
            int row = m0 + wr * 128 + mt * 16 + quad * 4;
            for (int nt = 0; nt < 4; ++nt) {
                int col = n0 + wc * 64 + nt * 16 + l16;
                float bv = isbf ? b2f(((const unsigned short*)biasraw)[col])
                                : ((const float*)biasraw)[col];
                for (int i = 0; i < 4; ++i)
                    qk[(row + i) * 2048 + col] = f2b(acc[mt][nt][i] + bv);
            }
        }
    } else if (n0 < 2048) {
        for (int mt = 0; mt < 8; ++mt) {
            int row = m0 + wr * 128 + mt * 16 + quad * 4;
            int tq = row & 2047, b = row >> 11;
            for (int nt = 0; nt < 4; ++nt) {
                int col = n0 + wc * 64 + nt * 16 + l16;
                float bv = isbf ? b2f(((const unsigned short*)biasraw)[col])
                                : ((const float*)biasraw)[col];
                int c = col - 1024;
                int hh = c >> 6, d = c & 63;
                int base = ((b * 16 + hh) * 32 + (tq >> 6)) * 4096
                         + ((tq >> 5) & 1) * 2048 + ((tq >> 4) & 1) * 1024
                         + (d >> 5) * 512 + ((d >> 3) & 3) * 128
                         + (tq & 15) * 8 + (d & 7);
                for (int i = 0; i < 4; ++i)
                    k2[base + i * 8] = f2b(acc[mt][nt][i] + bv);
            }
        }
    } else {
        for (int mt = 0; mt < 8; ++mt) {
            int row = m0 + wr * 128 + mt * 16 + quad * 4;
            int tq = row & 2047, b = row >> 11;
            for (int nt = 0; nt < 4; ++nt) {
                int col = n0 + wc * 64 + nt * 16 + l16;
                float bv = isbf ? b2f(((const unsigned short*)biasraw)[col])
                                : ((const float*)biasraw)[col];
                int c = col - 2048;
                int hh = c >> 6, d = c & 63;
                int base = ((b * 16 + hh) * 32 + (tq >> 6)) * 4096
                         + ((tq >> 5) & 1) * 2048 + (d >> 4) * 512
                         + ((tq >> 3) & 3) * 128 + (d & 15) * 8 + (tq & 7);
                u16x4 pk;
                for (int i = 0; i < 4; ++i) pk[i] = f2b(acc[mt][nt][i] + bv);
                *(u16x4*)&v2[base] = pk;
            }
        }
    }
}

// Split-kv causal flash attention v11 (unchanged from R13). Grid (32 bh, 32 y),
// 4 waves/block, 256 thr. Zero LDS staging, zero in-loop barriers; cross-trip
// QK/softmax pipeline with svA/svB ping-pong.
__global__ __launch_bounds__(256, 3) void k_attn(const unsigned short* __restrict__ qk,
                                                 const unsigned short* __restrict__ k2,
                                                 const unsigned short* __restrict__ v2,
                                                 const void* __restrict__ biasraw,
                                                 void* __restrict__ outv) {
    __shared__ __align__(16) float SMf[4416];   // 17664B epilogue merge buffer

    int tid  = threadIdx.x;
    int lane = tid & 63, wv = tid >> 6;
    int quad = lane >> 4, l16 = lane & 15;
    int isbf = detect_bf(biasraw, lane);
    int bh = blockIdx.x;
    int g  = 31 - blockIdx.y;
    int b = bh >> 4, h = bh & 15;
    int rowbase = b * TLEN;

    int s_ = wv >> 1;
    int p  = wv & 1;
    int qbase = 64 * g + 32 * s_;
    int T  = g + 1;
    int Tw = T - ((s_ == 0 && p == 1) ? 1 : 0);
    bool dmw = (p == s_);

    bf16x8 qf[2][2];
    for (int qt = 0; qt < 2; ++qt)
        for (int kh = 0; kh < 2; ++kh)
            qf[qt][kh] = *(const bf16x8*)&qk[(rowbase + qbase + qt * 16 + l16) * 2048
                                            + h * HS + kh * 32 + quad * 8];

    f32x4 o[2][4] = {};
    float ls[2] = {0.f, 0.f};

    const unsigned short* kp = k2 + bh * 131072 + p * 2048 + lane * 8;
    const unsigned short* vp = v2 + bh * 131072 + p * 2048 + lane * 8;

    bf16x8 kf00, kf01, kf10, kf11;
    f32x4 svA[2][2], svB[2][2];
    {
        bf16x8 k0a = *(const bf16x8*)kp;
        bf16x8 k0b = *(const bf16x8*)(kp + 512);
        bf16x8 k0c = *(const bf16x8*)(kp + 1024);
        bf16x8 k0d = *(const bf16x8*)(kp + 1536);
        kp += 4096;
        kf00 = *(const bf16x8*)kp;
        kf01 = *(const bf16x8*)(kp + 512);
        kf10 = *(const bf16x8*)(kp + 1024);
        kf11 = *(const bf16x8*)(kp + 1536);
        kp += 4096;
        #pragma unroll
        for (int qt = 0; qt < 2; ++qt) {
            f32x4 z0 = {};
            z0 = __builtin_amdgcn_mfma_f32_16x16x32_bf16(k0a, qf[qt][0], z0, 0, 0, 0);
            z0 = __builtin_amdgcn_mfma_f32_16x16x32_bf16(k0b, qf[qt][1], z0, 0, 0, 0);
            svA[qt][0] = z0;
            f32x4 z1 = {};
            z1 = __builtin_amdgcn_mfma_f32_16x16x32_bf16(k0c, qf[qt][0], z1, 0, 0, 0);
            z1 = __builtin_amdgcn_mfma_f32_16x16x32_bf16(k0d, qf[qt][1], z1, 0, 0, 0);
            svA[qt][1] = z1;
        }
    }

    auto trip = [&](f32x4 (&svin)[2][2], f32x4 (&svout)[2][2], int tt) {
        bf16x8 av0 = *(const bf16x8*)vp;
        bf16x8 av1 = *(const bf16x8*)(vp + 512);
        bf16x8 av2 = *(const bf16x8*)(vp + 1024);
        bf16x8 av3 = *(const bf16x8*)(vp + 1536);
        vp += 4096;

        __builtin_amdgcn_s_setprio(1);
        #pragma unroll
        for (int qt = 0; qt < 2; ++qt) {
            f32x4 z0 = {};
            z0 = __builtin_amdgcn_mfma_f32_16x16x32_bf16(kf00, qf[qt][0], z0, 0, 0, 0);
            z0 = __builtin_amdgcn_mfma_f32_16x16x32_bf16(kf01, qf[qt][1], z0, 0, 0, 0);
            svout[qt][0] = z0;
            f32x4 z1 = {};
            z1 = __builtin_amdgcn_mfma_f32_16x16x32_bf16(kf10, qf[qt][0], z1, 0, 0, 0);
            z1 = __builtin_amdgcn_mfma_f32_16x16x32_bf16(kf11, qf[qt][1], z1, 0, 0, 0);
            svout[qt][1] = z1;
        }
        __builtin_amdgcn_s_setprio(0);

        kf00 = *(const bf16x8*)kp;
        kf01 = *(const bf16x8*)(kp + 512);
        kf10 = *(const bf16x8*)(kp + 1024);
        kf11 = *(const bf16x8*)(kp + 1536);
        kp += 4096;

        unsigned sp[2][2][2];
        int kvb = tt * KVT + 32 * p;
        if (dmw && tt == T - 1) {
            #pragma unroll
            for (int qt = 0; qt < 2; ++qt) {
                float psum = 0.f;
                int q = qbase + qt * 16 + l16;
                #pragma unroll
                for (int nt = 0; nt < 2; ++nt) {
                    float pv[4];
                    #pragma unroll
                    for (int i = 0; i < 4; ++i) {
                        float arg = fmaf(svin[qt][nt][i], SCL, -12.0f);
                        int kv = kvb + nt * 16 + quad * 4 + i;
                        if (kv > q) arg = -1e30f;
                        pv[i] = fexp2(arg);
                        psum += pv[i];
                    }
                    sp[qt][nt][0] = pkbf(pv[0], pv[1]);
                    sp[qt][nt][1] = pkbf(pv[2], pv[3]);
                }
                ls[qt] += psum;
            }
        } else {
            #pragma unroll
            for (int qt = 0; qt < 2; ++qt) {
                float psum = 0.f;
                #pragma unroll
                for (int nt = 0; nt < 2; ++nt) {
                    float pv[4];
                    #pragma unroll
                    for (int i = 0; i < 4; ++i) {
                        float arg = fmaf(svin[qt][nt][i], SCL, -12.0f);
                        pv[i] = fexp2(arg);
                        psum += pv[i];
                    }
                    sp[qt][nt][0] = pkbf(pv[0], pv[1]);
                    sp[qt][nt][1] = pkbf(pv[2], pv[3]);
                }
                ls[qt] += psum;
            }
        }

        int qsel = quad & 2;
        bf16x8 f0 = xfrag(sp[0][0][0], sp[0][0][1], sp[0][1][0], sp[0][1][1], qsel);
        bf16x8 f1 = xfrag(sp[1][0][0], sp[1][0][1], sp[1][1][0], sp[1][1][1], qsel);
        __builtin_amdgcn_s_setprio(1);
        o[0][0] = __builtin_amdgcn_mfma_f32_16x16x32_bf16(av0, f0, o[0][0], 0, 0, 0);
        o[1][0] = __builtin_amdgcn_mfma_f32_16x16x32_bf16(av0, f1, o[1][0], 0, 0, 0);
        o[0][1] = __builtin_amdgcn_mfma_f32_16x16x32_bf16(av1, f0, o[0][1], 0, 0, 0);
        o[1][1] = __builtin_amdgcn_mfma_f32_16x16x32_bf16(av1, f1, o[1][1], 0, 0, 0);
        o[0][2] = __builtin_amdgcn_mfma_f32_16x16x32_bf16(av2, f0, o[0][2], 0, 0, 0);
        o[1][2] = __builtin_amdgcn_mfma_f32_16x16x32_bf16(av2, f1, o[1][2], 0, 0, 0);
        o[0][3] = __builtin_amdgcn_mfma_f32_16x16x32_bf16(av3, f0, o[0][3], 0, 0, 0);
        o[1][3] = __builtin_amdgcn_mfma_f32_16x16x32_bf16(av3, f1, o[1][3], 0, 0, 0);
        __builtin_amdgcn_s_setprio(0);
    };

    int t = 0;
    for (; t + 2 <= Tw; t += 2) {
        trip(svA, svB, t);
        trip(svB, svA, t + 1);
    }
    if (t < Tw) trip(svA, svB, t);

    #pragma unroll
    for (int qt = 0; qt < 2; ++qt) {
        ls[qt] += __shfl_xor(ls[qt], 16);
        ls[qt] += __shfl_xor(ls[qt], 32);
    }
    float* mrg  = SMf;
    float* lbuf = SMf + 4352;

    if (p == 1) {
        #pragma unroll
        for (int qt = 0; qt < 2; ++qt)
            #pragma unroll
            for (int dt = 0; dt < 4; ++dt)
                *(f32x4*)&mrg[s_ * (32 * 68) + (qt * 16 + l16) * 68 + dt * 16 + quad * 4] = o[qt][dt];
        if (quad == 0) {
            lbuf[s_ * 32 + l16]      = ls[0];
            lbuf[s_ * 32 + 16 + l16] = ls[1];
        }
    }
    __syncthreads();
    if (p == 0) {
        #pragma unroll
        for (int qt = 0; qt < 2; ++qt) {
            float lt = ls[qt] + lbuf[s_ * 32 + qt * 16 + l16];
            float inv = 1.0f / lt;
            int q = qbase + qt * 16 + l16;
            if (isbf) {
                unsigned short* out = (unsigned short*)outv;
                #pragma unroll
                for (int dt = 0; dt < 4; ++dt) {
                    f32x4 m = *(const f32x4*)&mrg[s_ * (32 * 68) + (qt * 16 + l16) * 68 + dt * 16 + quad * 4];
                    u16x4 ov;
                    #pragma unroll
                    for (int i = 0; i < 4; ++i) ov[i] = f2b((o[qt][dt][i] + m[i]) * inv);
                    *(u16x4*)&out[(rowbase + q) * CDIM + h * HS + dt * 16 + quad * 4] = ov;
                }
            } else {
                float* out = (float*)outv;
                #pragma unroll
                for (int dt = 0; dt < 4; ++dt) {
                    f32x4 m = *(const f32x4*)&mrg[s_ * (32 * 68) + (qt * 16 + l16) * 68 + dt * 16 + quad * 4];
                    float4 ov;
                    ov.x = (o[qt][dt][0] + m[0]) * inv;
                    ov.y = (o[qt][dt][1] + m[1]) * inv;
                    ov.z = (o[qt][dt][2] + m[2]) * inv;
                    ov.w = (o[qt][dt][3] + m[3]) * inv;
                    *(float4*)&out[(rowbase + q) * CDIM + h * HS + dt * 16 + quad * 4] = ov;
                }
            }
        }
    }
}

extern "C" void kernel_launch(void* const* d_in, const int* in_sizes, int n_in,
                              void* d_out, int out_size, void* d_ws, size_t ws_size,
                              hipStream_t stream) {
    const void* x    = d_in[0];
    const void* w    = d_in[1];
    const void* bias = d_in[2];

    char* ws = (char*)d_ws;
    unsigned short* xb  = (unsigned short*)ws;                   // 8 MB (fp32 path only)
    unsigned short* wt  = (unsigned short*)(ws + (8u  << 20));   // 6 MB
    unsigned short* qk  = (unsigned short*)(ws + (16u << 20));   // 16 MB (Q rows)
    unsigned short* k2  = (unsigned short*)(ws + (32u << 20));   // 8 MB (K fragment-order)
    unsigned short* v2  = (unsigned short*)(ws + (40u << 20));   // 8 MB (V fragment-order)

    k_prep<<<768, 256, 0, stream>>>(w, x, bias, wt, xb);
    k_gemm_qkv<<<192, 512, 0, stream>>>(x, xb, bias, wt, qk, k2, v2);
    k_attn<<<dim3(32, 32), 256, 0, stream>>>(qk, k2, v2, bias, d_out);
}